// Round 13
// baseline (354.262 us; speedup 1.0000x reference)
//
#include <hip/hip_runtime.h>
#include <hip/hip_bf16.h>
#include <cstddef>

// BS=8, NE=128, ENT=768, REL=768, RANK=256, OUT=256
// M = 131072 rows; rel row-major [b][i][j][768]
// ws: l1 [1024*256 f32] | l2 [1024*256 f32] | W3g [196608 bf16 frag] | Weg [65536 bf16 frag]
// Fragment-major B panels: flat = ((kq*256 + n)*4 + g)*8 + e (kq=k/32, g=(k/8)%4, e=k%8)
//
// fused_main R12 — LDS-FREE, BARRIER-FREE GEMM1:
//   R3-R11 post-mortem: every rel-through-LDS variant (9 schedules) pinned at
//   fused 180-250us, MfmaUtil ~11%, vs ~85us floor. Invariant = LDS staging:
//   barrier lockstep/K-step + vmcnt FIFO coupling + LDS pipe load.
//   Fix: the verified A-fragment rel[fm*16+c16][kq*32+g*8+e] is 8 CONSECUTIVE
//   f32 per lane -> 2 contiguous dwordx4 straight from global; 4 g-groups x 16
//   rows tile full cachelines (100% utilization). Load to regs, cvt in-reg
//   (pk8, verified path), MFMA directly. Zero LDS, zero barriers, zero manual
//   waitcnt in the K-loop; 2-generation reg dbuf (~16KB HBM in flight/wave).
//   W3g frag-major direct from L2 (verbatim). acc layout identical to R8-R11
//   -> epilogue/GEMM2/LN/store verbatim (verified mapping preserved).

typedef __attribute__((ext_vector_type(8))) short short8;
typedef __attribute__((ext_vector_type(4))) float f32x4;

__device__ __forceinline__ unsigned short f2bf(float x) {
  union { float f; unsigned u; } v; v.f = x;
  unsigned r = (v.u + 0x7FFFu + ((v.u >> 16) & 1u)) >> 16;  // RNE
  return (unsigned short)r;
}
__device__ __forceinline__ unsigned short cvt1(float x) {
  return __bfloat16_as_ushort(__float2bfloat16(x));  // pairs to v_cvt_pk_bf16_f32
}
__device__ __forceinline__ f32x4 mfma16(short8 a, short8 b, f32x4 c) {
  return __builtin_amdgcn_mfma_f32_16x16x32_bf16(a, b, c, 0, 0, 0);
}
__device__ __forceinline__ short8 pk8(f32x4 x, f32x4 y) {
  short8 s;
  s[0] = (short)cvt1(x[0]); s[1] = (short)cvt1(x[1]);
  s[2] = (short)cvt1(x[2]); s[3] = (short)cvt1(x[3]);
  s[4] = (short)cvt1(y[0]); s[5] = (short)cvt1(y[1]);
  s[6] = (short)cvt1(y[2]); s[7] = (short)cvt1(y[3]);
  return s;
}

// ---------------- prep (grid 1280) -------------------------------------------
__global__ __launch_bounds__(256) void prep_all(
    const float* __restrict__ sub, const float* __restrict__ obj,
    const float* __restrict__ W1, const float* __restrict__ b1,
    const float* __restrict__ W2, const float* __restrict__ b2,
    const float* __restrict__ W3, const float* __restrict__ We,
    float* __restrict__ l1p, float* __restrict__ l2p,
    unsigned short* __restrict__ W3g, unsigned short* __restrict__ Weg) {
  const int tid = threadIdx.x;
  if (blockIdx.x >= 256) {
    int idx = (blockIdx.x - 256) * 256 + tid;
    if (idx < 196608) {
      int n = idx / 768, k = idx % 768;
      int f = ((k >> 5) * 256 + n) * 32 + ((k >> 3) & 3) * 8 + (k & 7);
      W3g[f] = f2bf(W3[idx]);
    }
    int j = idx - 196608;
    if (j >= 0 && j < 65536) {
      int n = j / 256, k = j % 256;
      int f = ((k >> 5) * 256 + n) * 32 + ((k >> 3) & 3) * 8 + (k & 7);
      Weg[f] = f2bf(We[j]);
    }
    return;
  }
  const int half = blockIdx.x >> 7;
  const float* x = half ? obj : sub;
  const float* W = half ? W2 : W1;
  const float* bias = half ? b2 : b1;
  float* outp = half ? l2p : l1p;

  __shared__ float xs[8][768];
  const int R0 = (blockIdx.x & 127) * 8;
  #pragma unroll
  for (int c = 0; c < 6; ++c) {
    int f4i = c * 256 + tid;
    int row = f4i / 192;
    int c4 = f4i % 192;
    *(float4*)&xs[row][c4 * 4] = *(const float4*)&x[(size_t)(R0 + row) * 768 + c4 * 4];
  }
  __syncthreads();
  const int col = tid;
  const float* Wr = W + (size_t)col * 768;
  float a[8] = {0.f, 0.f, 0.f, 0.f, 0.f, 0.f, 0.f, 0.f};
  for (int k4 = 0; k4 < 192; ++k4) {
    float4 wv = *(const float4*)&Wr[k4 * 4];
    #pragma unroll
    for (int r = 0; r < 8; ++r) {
      float4 xv = *(const float4*)&xs[r][k4 * 4];
      a[r] += wv.x * xv.x + wv.y * xv.y + wv.z * xv.z + wv.w * xv.w;
    }
  }
  float bb = bias[col];
  #pragma unroll
  for (int r = 0; r < 8; ++r)
    outp[(size_t)(R0 + r) * 256 + col] = a[r] + bb;
}

// ---------------- fused main -------------------------------------------------
__global__ __launch_bounds__(256, 2) void fused_main(
    const float* __restrict__ rel, const float* __restrict__ l1p,
    const float* __restrict__ l2p, const unsigned short* __restrict__ W3g,
    const unsigned short* __restrict__ Weg, const float* __restrict__ b3,
    const float* __restrict__ be, const float* __restrict__ lng,
    const float* __restrict__ lnb, float* __restrict__ out) {
  __shared__ unsigned short prod[64][256];  // 32 KB, XOR-swizzled (only LDS)
  __shared__ float ps[64][4], pq[64][4], mus[64], rss[64];

  const int tid = threadIdx.x;
  const int wave = tid >> 6, lane = tid & 63;
  const int g = lane >> 4, c16 = lane & 15;

  // XCD-bijective swizzle (2048 % 8 == 0)
  const int bid = (blockIdx.x & 7) * 256 + (blockIdx.x >> 3);
  const int R0 = bid * 64;
  const int b = R0 >> 14;
  const int rem = R0 & 16383;
  const int i = rem >> 7;
  const int j0 = rem & 127;  // 0 or 64

  const float* relBase = rel + (size_t)((b * 128 + i) * 128 + j0) * 768;

  // per-lane rel fragment pointers: row = fm*16 + c16, k-offset g*8
  const float* rp0 = relBase + (size_t)c16 * 768 + g * 8;
  // W3g frag-major: per-lane base for n = wave*64 + fn*16 + c16
  const unsigned short* bp = W3g + (size_t)(wave * 64 + c16) * 32 + g * 8;

  f32x4 acc1[4][4] = {};
  f32x4 ra[2][4][2];  // [gen][fm][half] rel f32 prefetch
  short8 Bw[2][4];    // [gen][fn] W3 fragments

#define LOADREL(G, KQ)                                                         \
  {                                                                            \
    _Pragma("unroll") for (int fm = 0; fm < 4; ++fm) {                         \
      const float* p_ = rp0 + fm * (16 * 768) + (KQ) * 32;                     \
      ra[G][fm][0] = *(const f32x4*)(p_);                                      \
      ra[G][fm][1] = *(const f32x4*)(p_ + 4);                                  \
    }                                                                          \
  }
#define LOADW(G, KQ)                                                           \
  {                                                                            \
    _Pragma("unroll") for (int fn = 0; fn < 4; ++fn)                           \
        Bw[G][fn] = *(const short8*)(bp + (size_t)(KQ) * 8192 + fn * 512);     \
  }

  // prologue: 2 generations in flight
  LOADREL(0, 0); LOADW(0, 0);
  LOADREL(1, 1); LOADW(1, 1);

  #pragma unroll
  for (int kq = 0; kq < 24; ++kq) {
    const int cur = kq & 1;
    // cvt rel(kq) to bf16 frags (compiler inserts counted vmcnt; ~2-iter window)
    short8 ah[4];
    #pragma unroll
    for (int fm = 0; fm < 4; ++fm) ah[fm] = pk8(ra[cur][fm][0], ra[cur][fm][1]);
    // MFMA tile kq (Bw[cur] latched at issue; safe to refill after)
    #pragma unroll
    for (int fn = 0; fn < 4; ++fn)
      #pragma unroll
      for (int fm = 0; fm < 4; ++fm)
        acc1[fm][fn] = mfma16(ah[fm], Bw[cur][fn], acc1[fm][fn]);
    // prefetch generation kq+2 into the buffers just consumed
    if (kq < 22) {
      LOADREL(cur, kq + 2);
      LOADW(cur, kq + 2);
    }
  }

  // ---- epilogue 1: prod = (l3 + b3) * l1 * l2 -> bf16 swizzled LDS ----
  const int colb = wave * 64 + c16;
  const float* l1row = l1p + (size_t)(b * 128 + i) * 256;
  float l1v[4], b3v[4];
  #pragma unroll
  for (int fn = 0; fn < 4; ++fn) {
    l1v[fn] = l1row[colb + fn * 16];
    b3v[fn] = b3[colb + fn * 16];
  }
  #pragma unroll
  for (int fm = 0; fm < 4; ++fm) {
    #pragma unroll
    for (int r = 0; r < 4; ++r) {
      const int m = fm * 16 + g * 4 + r;
      const float* l2row = l2p + (size_t)(b * 128 + j0 + m) * 256;
      #pragma unroll
      for (int fn = 0; fn < 4; ++fn) {
        float v = (acc1[fm][fn][r] + b3v[fn]) * l1v[fn] * l2row[colb + fn * 16];
        prod[m][(colb + fn * 16) ^ ((m & 7) << 3)] = f2bf(v);
      }
    }
  }
  __syncthreads();

  // ---- GEMM2: f = prod @ Web^T (Weg fragment-major) ----
  f32x4 acc2[4][4] = {};
  #pragma unroll
  for (int kk = 0; kk < 8; ++kk) {
    short8 a2[4];
    #pragma unroll
    for (int fm = 0; fm < 4; ++fm) {
      const int m = fm * 16 + c16;
      a2[fm] = *(const short8*)&prod[m][(kk * 32 + g * 8) ^ ((m & 7) << 3)];
    }
    #pragma unroll
    for (int fn = 0; fn < 4; ++fn) {
      const int n = wave * 64 + fn * 16 + c16;
      short8 bfr = *(const short8*)&Weg[(size_t)((kk * 256 + n) * 4 + g) * 8];
      #pragma unroll
      for (int fm = 0; fm < 4; ++fm)
        acc2[fm][fn] = mfma16(a2[fm], bfr, acc2[fm][fn]);
    }
  }

  // ---- LN stats: per-row sum/sumsq; 16-lane shfl reduce + cross-wave LDS ----
  float bev[4];
  #pragma unroll
  for (int fn = 0; fn < 4; ++fn) bev[fn] = be[colb + fn * 16];
  #pragma unroll
  for (int fm = 0; fm < 4; ++fm) {
    #pragma unroll
    for (int r = 0; r < 4; ++r) {
      float s1 = 0.f, s2 = 0.f;
      #pragma unroll
      for (int fn = 0; fn < 4; ++fn) {
        float v = acc2[fm][fn][r] + bev[fn];
        s1 += v; s2 += v * v;
      }
      #pragma unroll
      for (int off = 1; off < 16; off <<= 1) {
        s1 += __shfl_xor(s1, off);
        s2 += __shfl_xor(s2, off);
      }
      if (c16 == 0) {
        const int m = fm * 16 + g * 4 + r;
        ps[m][wave] = s1; pq[m][wave] = s2;
      }
    }
  }
  __syncthreads();
  if (tid < 64) {
    float s = ps[tid][0] + ps[tid][1] + ps[tid][2] + ps[tid][3];
    float q = pq[tid][0] + pq[tid][1] + pq[tid][2] + pq[tid][3];
    float mu = s * 0.00390625f;
    float var = q * 0.00390625f - mu * mu;
    mus[tid] = mu;
    rss[tid] = rsqrtf(var + 1e-6f);
  }
  __syncthreads();

  // ---- store: (f - mu)*rs*g + b ----
  float gv[4], bhv[4];
  #pragma unroll
  for (int fn = 0; fn < 4; ++fn) {
    gv[fn] = lng[colb + fn * 16];
    bhv[fn] = lnb[colb + fn * 16];
  }
  #pragma unroll
  for (int fm = 0; fm < 4; ++fm) {
    #pragma unroll
    for (int r = 0; r < 4; ++r) {
      const int m = fm * 16 + g * 4 + r;
      const float mu = mus[m], rs = rss[m];
      float* orow = out + (size_t)(R0 + m) * 256;
      #pragma unroll
      for (int fn = 0; fn < 4; ++fn) {
        float v = acc2[fm][fn][r] + bev[fn];
        orow[colb + fn * 16] = (v - mu) * rs * gv[fn] + bhv[fn];
      }
    }
  }
#undef LOADREL
#undef LOADW
}

extern "C" void kernel_launch(void* const* d_in, const int* in_sizes, int n_in,
                              void* d_out, int out_size, void* d_ws, size_t ws_size,
                              hipStream_t stream) {
  const float* sub = (const float*)d_in[0];
  const float* obj = (const float*)d_in[1];
  const float* rel = (const float*)d_in[2];
  const float* W1 = (const float*)d_in[3];
  const float* b1 = (const float*)d_in[4];
  const float* W2 = (const float*)d_in[5];
  const float* b2 = (const float*)d_in[6];
  const float* W3 = (const float*)d_in[7];
  const float* b3 = (const float*)d_in[8];
  const float* We = (const float*)d_in[9];
  const float* be = (const float*)d_in[10];
  const float* lng = (const float*)d_in[11];
  const float* lnb = (const float*)d_in[12];
  float* out = (float*)d_out;

  float* ws = (float*)d_ws;
  float* l1p = ws;
  float* l2p = ws + 262144;
  unsigned short* W3g = (unsigned short*)(ws + 524288);
  unsigned short* Weg = W3g + 196608;

  prep_all<<<1280, 256, 0, stream>>>(sub, obj, W1, b1, W2, b2, W3, We, l1p, l2p, W3g, Weg);
  fused_main<<<2048, 256, 0, stream>>>(rel, l1p, l2p, W3g, Weg, b3, be, lng, lnb, out);
}

// Round 14
// 333.844 us; speedup vs baseline: 1.0612x; 1.0612x over previous
//
#include <hip/hip_runtime.h>
#include <hip/hip_bf16.h>
#include <cstddef>

// BS=8, NE=128, ENT=768, REL=768, RANK=256, OUT=256
// M = 131072 rows; rel row-major [b][i][j][768]
// ws: l1 [1024*256 f32] | l2 [1024*256 f32] | W3g [196608 bf16 frag] | Weg [65536 bf16 frag]
//     | prodG [131072*256 bf16] (67 MB, only if ws_size permits)
// Fragment-major B panels: flat = ((kq*256 + n)*4 + g)*8 + e (kq=k/32, g=(k/8)%4, e=k%8)
//
// R14 — DIAGNOSTIC SPLIT (ablate empirically, Common-mistake #8):
//   gemm1_prod: R9's verified K-loop (best measured, 203.7 total) + triple-product
//               epilogue + coalesced bf16 prod writeout. LDS 32 KB -> 4 blocks/CU.
//   gemm2_ln:   pure streaming GEMM2+LN. NO LDS, NO barriers: wave owns 16 rows,
//               A-frags direct from global (64B/row/kk, L1-paired across kk),
//               Weg frag-major L2-hot, LN wave-local via shfl_xor(1,2,4,8).
//   Fallback:   if ws_size < ~67 MB, run fused_mono (R9 kernel verbatim).

typedef __attribute__((ext_vector_type(8))) short short8;
typedef __attribute__((ext_vector_type(4))) float f32x4;

__device__ __forceinline__ unsigned short f2bf(float x) {
  union { float f; unsigned u; } v; v.f = x;
  unsigned r = (v.u + 0x7FFFu + ((v.u >> 16) & 1u)) >> 16;  // RNE
  return (unsigned short)r;
}
__device__ __forceinline__ unsigned short cvt1(float x) {
  return __bfloat16_as_ushort(__float2bfloat16(x));  // pairs to v_cvt_pk_bf16_f32
}
__device__ __forceinline__ f32x4 mfma16(short8 a, short8 b, f32x4 c) {
  return __builtin_amdgcn_mfma_f32_16x16x32_bf16(a, b, c, 0, 0, 0);
}
__device__ __forceinline__ short8 pk8(f32x4 x, f32x4 y) {
  short8 s;
  s[0] = (short)cvt1(x[0]); s[1] = (short)cvt1(x[1]);
  s[2] = (short)cvt1(x[2]); s[3] = (short)cvt1(x[3]);
  s[4] = (short)cvt1(y[0]); s[5] = (short)cvt1(y[1]);
  s[6] = (short)cvt1(y[2]); s[7] = (short)cvt1(y[3]);
  return s;
}

// ---------------- prep (grid 1280) -------------------------------------------
__global__ __launch_bounds__(256) void prep_all(
    const float* __restrict__ sub, const float* __restrict__ obj,
    const float* __restrict__ W1, const float* __restrict__ b1,
    const float* __restrict__ W2, const float* __restrict__ b2,
    const float* __restrict__ W3, const float* __restrict__ We,
    float* __restrict__ l1p, float* __restrict__ l2p,
    unsigned short* __restrict__ W3g, unsigned short* __restrict__ Weg) {
  const int tid = threadIdx.x;
  if (blockIdx.x >= 256) {
    int idx = (blockIdx.x - 256) * 256 + tid;
    if (idx < 196608) {
      int n = idx / 768, k = idx % 768;
      int f = ((k >> 5) * 256 + n) * 32 + ((k >> 3) & 3) * 8 + (k & 7);
      W3g[f] = f2bf(W3[idx]);
    }
    int j = idx - 196608;
    if (j >= 0 && j < 65536) {
      int n = j / 256, k = j % 256;
      int f = ((k >> 5) * 256 + n) * 32 + ((k >> 3) & 3) * 8 + (k & 7);
      Weg[f] = f2bf(We[j]);
    }
    return;
  }
  const int half = blockIdx.x >> 7;
  const float* x = half ? obj : sub;
  const float* W = half ? W2 : W1;
  const float* bias = half ? b2 : b1;
  float* outp = half ? l2p : l1p;

  __shared__ float xs[8][768];
  const int R0 = (blockIdx.x & 127) * 8;
  #pragma unroll
  for (int c = 0; c < 6; ++c) {
    int f4i = c * 256 + tid;
    int row = f4i / 192;
    int c4 = f4i % 192;
    *(float4*)&xs[row][c4 * 4] = *(const float4*)&x[(size_t)(R0 + row) * 768 + c4 * 4];
  }
  __syncthreads();
  const int col = tid;
  const float* Wr = W + (size_t)col * 768;
  float a[8] = {0.f, 0.f, 0.f, 0.f, 0.f, 0.f, 0.f, 0.f};
  for (int k4 = 0; k4 < 192; ++k4) {
    float4 wv = *(const float4*)&Wr[k4 * 4];
    #pragma unroll
    for (int r = 0; r < 8; ++r) {
      float4 xv = *(const float4*)&xs[r][k4 * 4];
      a[r] += wv.x * xv.x + wv.y * xv.y + wv.z * xv.z + wv.w * xv.w;
    }
  }
  float bb = bias[col];
  #pragma unroll
  for (int r = 0; r < 8; ++r)
    outp[(size_t)(R0 + r) * 256 + col] = a[r] + bb;
}

// ======================= split kernel A: GEMM1 -> prod ========================
__global__ __launch_bounds__(256, 4) void gemm1_prod(
    const float* __restrict__ rel, const float* __restrict__ l1p,
    const float* __restrict__ l2p, const unsigned short* __restrict__ W3g,
    const float* __restrict__ b3, unsigned short* __restrict__ prodG) {
  __shared__ union U {
    unsigned short stg[2][64][64];  // 16 KB bf16 staging (verified layout)
    unsigned short prod[64][256];   // 32 KB
  } u;

  const int tid = threadIdx.x;
  const int wave = tid >> 6, lane = tid & 63;
  const int g = lane >> 4, c16 = lane & 15;

  const int bid = (blockIdx.x & 7) * 256 + (blockIdx.x >> 3);  // XCD swizzle
  const int R0 = bid * 64;
  const int b = R0 >> 14;
  const int rem = R0 & 16383;
  const int i = rem >> 7;
  const int j0 = rem & 127;

  const float* relBase = rel + (size_t)((b * 128 + i) * 128 + j0) * 768;

  const int sr4 = lane >> 2, c4 = lane & 3;
  const int rr = wave * 16 + sr4;
  const float* aG = relBase + (size_t)rr * 768 + c4 * 16;
  unsigned short* stW0 = &u.stg[0][rr][((c4 * 2) ^ (rr & 7)) * 8];
  unsigned short* stW1 = &u.stg[0][rr][((c4 * 2 + 1) ^ (rr & 7)) * 8];

  const unsigned short* bp = W3g + (size_t)(wave * 64 + c16) * 32 + g * 8;

  f32x4 acc1[4][4] = {};
  f32x4 av[2][4];

#define SCHED0_A __builtin_amdgcn_sched_barrier(0)
#define RAW_BARRIER_A                                         \
  do {                                                        \
    SCHED0_A;                                                 \
    asm volatile("s_waitcnt lgkmcnt(0)" ::: "memory");        \
    SCHED0_A;                                                 \
    __builtin_amdgcn_s_barrier();                             \
    SCHED0_A;                                                 \
  } while (0)

  // prologue: A(0) -> buf0 (via av[1] temp), A(1) -> av[0] in flight
  {
    const float* p0 = aG;
    av[1][0] = *(const f32x4*)(p0);
    av[1][1] = *(const f32x4*)(p0 + 4);
    av[1][2] = *(const f32x4*)(p0 + 8);
    av[1][3] = *(const f32x4*)(p0 + 12);
    const float* p1 = aG + 64;
    av[0][0] = *(const f32x4*)(p1);
    av[0][1] = *(const f32x4*)(p1 + 4);
    av[0][2] = *(const f32x4*)(p1 + 8);
    av[0][3] = *(const f32x4*)(p1 + 12);
    *(short8*)stW0 = pk8(av[1][0], av[1][1]);
    *(short8*)stW1 = pk8(av[1][2], av[1][3]);
  }
  RAW_BARRIER_A;

  #pragma unroll
  for (int ks = 0; ks < 12; ++ks) {
    const int buf = ks & 1;
    short8 B_[8];
    #pragma unroll
    for (int sub = 0; sub < 2; ++sub)
      #pragma unroll
      for (int fn = 0; fn < 4; ++fn)
        B_[sub * 4 + fn] =
            *(const short8*)(bp + (size_t)(ks * 2 + sub) * 8192 + fn * 512);
    SCHED0_A;
    if (ks <= 9) {
      const float* p = aG + (size_t)(ks + 2) * 64;
      av[(ks + 1) & 1][0] = *(const f32x4*)(p);
      av[(ks + 1) & 1][1] = *(const f32x4*)(p + 4);
      av[(ks + 1) & 1][2] = *(const f32x4*)(p + 8);
      av[(ks + 1) & 1][3] = *(const f32x4*)(p + 12);
    }
    SCHED0_A;
    #pragma unroll
    for (int sub = 0; sub < 2; ++sub) {
      #pragma unroll
      for (int fm = 0; fm < 4; ++fm) {
        const int r = fm * 16 + c16;
        short8 ah = *(const short8*)&u.stg[buf][r][((sub * 4 + g) ^ (r & 7)) * 8];
        #pragma unroll
        for (int fn = 0; fn < 4; ++fn)
          acc1[fm][fn] = mfma16(ah, B_[sub * 4 + fn], acc1[fm][fn]);
      }
    }
    SCHED0_A;
    if (ks <= 10) {
      const int nb = (buf ^ 1) * 4096;
      *(short8*)(stW0 + nb) = pk8(av[ks & 1][0], av[ks & 1][1]);
      *(short8*)(stW1 + nb) = pk8(av[ks & 1][2], av[ks & 1][3]);
      RAW_BARRIER_A;
    }
  }
  __syncthreads();

  // ---- epilogue: prod = (l3 + b3) * l1 * l2 -> bf16 swizzled LDS ----
  const int colb = wave * 64 + c16;
  const float* l1row = l1p + (size_t)(b * 128 + i) * 256;
  float l1v[4], b3v[4];
  #pragma unroll
  for (int fn = 0; fn < 4; ++fn) {
    l1v[fn] = l1row[colb + fn * 16];
    b3v[fn] = b3[colb + fn * 16];
  }
  #pragma unroll
  for (int fm = 0; fm < 4; ++fm) {
    #pragma unroll
    for (int r = 0; r < 4; ++r) {
      const int m = fm * 16 + g * 4 + r;
      const float* l2row = l2p + (size_t)(b * 128 + j0 + m) * 256;
      #pragma unroll
      for (int fn = 0; fn < 4; ++fn) {
        float v = (acc1[fm][fn][r] + b3v[fn]) * l1v[fn] * l2row[colb + fn * 16];
        u.prod[m][(colb + fn * 16) ^ ((m & 7) << 3)] = f2bf(v);
      }
    }
  }
  __syncthreads();

  // ---- coalesced copy-out: 8 rounds x (256 thr x 16 B) ----
  #pragma unroll
  for (int rnd = 0; rnd < 8; ++rnd) {
    const int m = rnd * 8 + (tid >> 5);
    const int c0 = (tid & 31) * 8;
    *(short8*)&prodG[(size_t)(R0 + m) * 256 + c0] =
        *(const short8*)&u.prod[m][c0 ^ ((m & 7) << 3)];
  }
#undef SCHED0_A
#undef RAW_BARRIER_A
}

// ======================= split kernel B: prod -> GEMM2+LN =====================
__global__ __launch_bounds__(256) void gemm2_ln(
    const unsigned short* __restrict__ prodG, const unsigned short* __restrict__ Weg,
    const float* __restrict__ be, const float* __restrict__ lng,
    const float* __restrict__ lnb, float* __restrict__ out) {
  const int tid = threadIdx.x;
  const int wave = tid >> 6, lane = tid & 63;
  const int g = lane >> 4, c16 = lane & 15;

  const int row16 = blockIdx.x * 64 + wave * 16;  // wave-owned 16 rows
  const unsigned short* ap = prodG + (size_t)(row16 + c16) * 256 + g * 8;
  const unsigned short* bp = Weg + (size_t)c16 * 32 + g * 8;

  f32x4 acc2[16] = {};
  #pragma unroll
  for (int kk = 0; kk < 8; ++kk) {
    short8 a2 = *(const short8*)(ap + kk * 32);
    #pragma unroll
    for (int fn = 0; fn < 16; ++fn) {
      short8 bfr = *(const short8*)(bp + kk * 8192 + fn * 512);
      acc2[fn] = mfma16(a2, bfr, acc2[fn]);
    }
  }

  float bev[16], gv[16], bhv[16];
  #pragma unroll
  for (int fn = 0; fn < 16; ++fn) {
    bev[fn] = be[fn * 16 + c16];
    gv[fn] = lng[fn * 16 + c16];
    bhv[fn] = lnb[fn * 16 + c16];
  }

  // LN: rows row16 + g*4 + r; reduce over fn (in-lane) + c16 (shfl_xor 1,2,4,8)
  #pragma unroll
  for (int r = 0; r < 4; ++r) {
    float s1 = 0.f, s2 = 0.f;
    #pragma unroll
    for (int fn = 0; fn < 16; ++fn) {
      float v = acc2[fn][r] + bev[fn];
      s1 += v; s2 += v * v;
    }
    #pragma unroll
    for (int off = 1; off < 16; off <<= 1) {
      s1 += __shfl_xor(s1, off);
      s2 += __shfl_xor(s2, off);
    }
    const float mu = s1 * 0.00390625f;
    const float rs = rsqrtf(s2 * 0.00390625f - mu * mu + 1e-6f);
    float* orow = out + (size_t)(row16 + g * 4 + r) * 256;
    #pragma unroll
    for (int fn = 0; fn < 16; ++fn) {
      float v = acc2[fn][r] + bev[fn];
      orow[fn * 16 + c16] = (v - mu) * rs * gv[fn] + bhv[fn];
    }
  }
}

// ======================= fallback: monolithic R9 (203.7 us) ===================
__global__ __launch_bounds__(256, 3) void fused_mono(
    const float* __restrict__ rel, const float* __restrict__ l1p,
    const float* __restrict__ l2p, const unsigned short* __restrict__ W3g,
    const unsigned short* __restrict__ Weg, const float* __restrict__ b3,
    const float* __restrict__ be, const float* __restrict__ lng,
    const float* __restrict__ lnb, float* __restrict__ out) {
  __shared__ union U {
    unsigned short stg[2][64][64];
    unsigned short prod[64][256];
  } u;
  __shared__ float l1s[256], b3s[256], bes[256], gs[256], bsh[256];
  __shared__ float ps[64][4], pq[64][4], mus[64], rss[64];

  const int tid = threadIdx.x;
  const int wave = tid >> 6, lane = tid & 63;
  const int g = lane >> 4, c16 = lane & 15;

  const int bid = (blockIdx.x & 7) * 256 + (blockIdx.x >> 3);
  const int R0 = bid * 64;
  const int b = R0 >> 14;
  const int rem = R0 & 16383;
  const int i = rem >> 7;
  const int j0 = rem & 127;

  const float* relBase = rel + (size_t)((b * 128 + i) * 128 + j0) * 768;

  l1s[tid] = l1p[(b * 128 + i) * 256 + tid];
  b3s[tid] = b3[tid];
  bes[tid] = be[tid];
  gs[tid] = lng[tid];
  bsh[tid] = lnb[tid];

  const int sr4 = lane >> 2, c4 = lane & 3;
  const int rr = wave * 16 + sr4;
  const float* aG = relBase + (size_t)rr * 768 + c4 * 16;
  unsigned short* stW0 = &u.stg[0][rr][((c4 * 2) ^ (rr & 7)) * 8];
  unsigned short* stW1 = &u.stg[0][rr][((c4 * 2 + 1) ^ (rr & 7)) * 8];

  const unsigned short* bp = W3g + (size_t)(wave * 64 + c16) * 32 + g * 8;

  f32x4 acc1[4][4] = {};
  f32x4 av[2][4];

#define SCHED0_M __builtin_amdgcn_sched_barrier(0)
#define RAW_BARRIER_M                                         \
  do {                                                        \
    SCHED0_M;                                                 \
    asm volatile("s_waitcnt lgkmcnt(0)" ::: "memory");        \
    SCHED0_M;                                                 \
    __builtin_amdgcn_s_barrier();                             \
    SCHED0_M;                                                 \
  } while (0)

  {
    const float* p0 = aG;
    av[1][0] = *(const f32x4*)(p0);
    av[1][1] = *(const f32x4*)(p0 + 4);
    av[1][2] = *(const f32x4*)(p0 + 8);
    av[1][3] = *(const f32x4*)(p0 + 12);
    const float* p1 = aG + 64;
    av[0][0] = *(const f32x4*)(p1);
    av[0][1] = *(const f32x4*)(p1 + 4);
    av[0][2] = *(const f32x4*)(p1 + 8);
    av[0][3] = *(const f32x4*)(p1 + 12);
    *(short8*)stW0 = pk8(av[1][0], av[1][1]);
    *(short8*)stW1 = pk8(av[1][2], av[1][3]);
  }
  RAW_BARRIER_M;

  #pragma unroll
  for (int ks = 0; ks < 12; ++ks) {
    const int buf = ks & 1;
    short8 B_[8];
    #pragma unroll
    for (int sub = 0; sub < 2; ++sub)
      #pragma unroll
      for (int fn = 0; fn < 4; ++fn)
        B_[sub * 4 + fn] =
            *(const short8*)(bp + (size_t)(ks * 2 + sub) * 8192 + fn * 512);
    SCHED0_M;
    if (ks <= 9) {
      const float* p = aG + (size_t)(ks + 2) * 64;
      av[(ks + 1) & 1][0] = *(const f32x4*)(p);
      av[(ks + 1) & 1][1] = *(const f32x4*)(p + 4);
      av[(ks + 1) & 1][2] = *(const f32x4*)(p + 8);
      av[(ks + 1) & 1][3] = *(const f32x4*)(p + 12);
    }
    SCHED0_M;
    #pragma unroll
    for (int sub = 0; sub < 2; ++sub) {
      #pragma unroll
      for (int fm = 0; fm < 4; ++fm) {
        const int r = fm * 16 + c16;
        short8 ah = *(const short8*)&u.stg[buf][r][((sub * 4 + g) ^ (r & 7)) * 8];
        #pragma unroll
        for (int fn = 0; fn < 4; ++fn)
          acc1[fm][fn] = mfma16(ah, B_[sub * 4 + fn], acc1[fm][fn]);
      }
    }
    SCHED0_M;
    if (ks <= 10) {
      const int nb = (buf ^ 1) * 4096;
      *(short8*)(stW0 + nb) = pk8(av[ks & 1][0], av[ks & 1][1]);
      *(short8*)(stW1 + nb) = pk8(av[ks & 1][2], av[ks & 1][3]);
      RAW_BARRIER_M;
    }
  }
  __syncthreads();

  #pragma unroll
  for (int fm = 0; fm < 4; ++fm) {
    #pragma unroll
    for (int r = 0; r < 4; ++r) {
      const int m = fm * 16 + g * 4 + r;
      const float* l2row = l2p + (size_t)(b * 128 + j0 + m) * 256;
      #pragma unroll
      for (int fn = 0; fn < 4; ++fn) {
        const int col = wave * 64 + fn * 16 + c16;
        float v = (acc1[fm][fn][r] + b3s[col]) * l1s[col] * l2row[col];
        u.prod[m][col ^ ((m & 7) << 3)] = f2bf(v);
      }
    }
  }
  __syncthreads();

  f32x4 acc2[4][4] = {};
  #pragma unroll
  for (int kk = 0; kk < 8; ++kk) {
    short8 a2[4];
    #pragma unroll
    for (int fm = 0; fm < 4; ++fm) {
      const int m = fm * 16 + c16;
      a2[fm] = *(const short8*)&u.prod[m][(kk * 32 + g * 8) ^ ((m & 7) << 3)];
    }
    #pragma unroll
    for (int fn = 0; fn < 4; ++fn) {
      const int n = wave * 64 + fn * 16 + c16;
      short8 bfr = *(const short8*)&Weg[(size_t)((kk * 256 + n) * 4 + g) * 8];
      #pragma unroll
      for (int fm = 0; fm < 4; ++fm)
        acc2[fm][fn] = mfma16(a2[fm], bfr, acc2[fm][fn]);
    }
  }

  #pragma unroll
  for (int fm = 0; fm < 4; ++fm) {
    #pragma unroll
    for (int r = 0; r < 4; ++r) {
      float s1 = 0.f, s2 = 0.f;
      #pragma unroll
      for (int fn = 0; fn < 4; ++fn) {
        const int col = wave * 64 + fn * 16 + c16;
        float v = acc2[fm][fn][r] + bes[col];
        s1 += v; s2 += v * v;
      }
      #pragma unroll
      for (int off = 1; off < 16; off <<= 1) {
        s1 += __shfl_xor(s1, off);
        s2 += __shfl_xor(s2, off);
      }
      if (c16 == 0) {
        const int m = fm * 16 + g * 4 + r;
        ps[m][wave] = s1; pq[m][wave] = s2;
      }
    }
  }
  __syncthreads();
  if (tid < 64) {
    float s = ps[tid][0] + ps[tid][1] + ps[tid][2] + ps[tid][3];
    float q = pq[tid][0] + pq[tid][1] + pq[tid][2] + pq[tid][3];
    float mu = s * 0.00390625f;
    float var = q * 0.00390625f - mu * mu;
    mus[tid] = mu;
    rss[tid] = rsqrtf(var + 1e-6f);
  }
  __syncthreads();

  #pragma unroll
  for (int fm = 0; fm < 4; ++fm) {
    #pragma unroll
    for (int r = 0; r < 4; ++r) {
      const int m = fm * 16 + g * 4 + r;
      const float mu = mus[m], rs = rss[m];
      float* orow = out + (size_t)(R0 + m) * 256;
      #pragma unroll
      for (int fn = 0; fn < 4; ++fn) {
        const int col = wave * 64 + fn * 16 + c16;
        float v = acc2[fm][fn][r] + bes[col];
        orow[col] = (v - mu) * rs * gs[col] + bsh[col];
      }
    }
  }
#undef SCHED0_M
#undef RAW_BARRIER_M
}

extern "C" void kernel_launch(void* const* d_in, const int* in_sizes, int n_in,
                              void* d_out, int out_size, void* d_ws, size_t ws_size,
                              hipStream_t stream) {
  const float* sub = (const float*)d_in[0];
  const float* obj = (const float*)d_in[1];
  const float* rel = (const float*)d_in[2];
  const float* W1 = (const float*)d_in[3];
  const float* b1 = (const float*)d_in[4];
  const float* W2 = (const float*)d_in[5];
  const float* b2 = (const float*)d_in[6];
  const float* W3 = (const float*)d_in[7];
  const float* b3 = (const float*)d_in[8];
  const float* We = (const float*)d_in[9];
  const float* be = (const float*)d_in[10];
  const float* lng = (const float*)d_in[11];
  const float* lnb = (const float*)d_in[12];
  float* out = (float*)d_out;

  float* ws = (float*)d_ws;
  float* l1p = ws;                                        // 1 MB
  float* l2p = ws + 262144;                               // 1 MB
  unsigned short* W3g = (unsigned short*)(ws + 524288);   // 384 KB
  unsigned short* Weg = W3g + 196608;                     // 128 KB
  unsigned short* prodG = (unsigned short*)(ws + 655360); // 67 MB
  const size_t need = 2621440ull + 67108864ull;

  prep_all<<<1280, 256, 0, stream>>>(sub, obj, W1, b1, W2, b2, W3, We, l1p, l2p, W3g, Weg);
  if (ws_size >= need) {
    gemm1_prod<<<2048, 256, 0, stream>>>(rel, l1p, l2p, W3g, b3, prodG);
    gemm2_ln<<<2048, 256, 0, stream>>>(prodG, Weg, be, lng, lnb, out);
  } else {
    fused_mono<<<2048, 256, 0, stream>>>(rel, l1p, l2p, W3g, Weg, b3, be, lng, lnb, out);
  }
}

// Round 15
// 211.571 us; speedup vs baseline: 1.6744x; 1.5779x over previous
//
#include <hip/hip_runtime.h>
#include <hip/hip_bf16.h>
#include <cstddef>

// BS=8, NE=128, ENT=768, REL=768, RANK=256, OUT=256
// M = 131072 rows; rel row-major [b][i][j][768]
// ws: l1 [1024*256 f32] | l2 [1024*256 f32] | W3g [196608 bf16 frag] | Weg [65536 bf16 frag]
// Fragment-major B panels: flat = ((kq*256 + n)*4 + g)*8 + e (kq=k/32, g=(k/8)%4, e=k%8)
//
// R15 — R9 trimmed to <=128 unified regs for 4 waves/SIMD:
//   Analysis: R9 K-loop is ~issue-bound at 3 waves/SIMD (430 issue-cy/wave/iter,
//   measured 1575 cy/CU-iter vs 1290 floor); occupancy was register-capped
//   (~150 live regs). Cuts: av 2-gen -> 1-gen (-16), LDS mirrors dropped
//   (epilogue reads small vectors direct from L2), launch_bounds(256,4).
//   Keeps: verified bf16 staging layout + swizzle, B-first FIFO order,
//   1 raw (lgkm-only) barrier/iter, XCD-bijective block swizzle.
//   Adds: s_setprio(1) around MFMA cluster (T5; 4 blocks now phase-diverse).

typedef __attribute__((ext_vector_type(8))) short short8;
typedef __attribute__((ext_vector_type(4))) float f32x4;

__device__ __forceinline__ unsigned short f2bf(float x) {
  union { float f; unsigned u; } v; v.f = x;
  unsigned r = (v.u + 0x7FFFu + ((v.u >> 16) & 1u)) >> 16;  // RNE
  return (unsigned short)r;
}
__device__ __forceinline__ unsigned short cvt1(float x) {
  return __bfloat16_as_ushort(__float2bfloat16(x));  // pairs to v_cvt_pk_bf16_f32
}
__device__ __forceinline__ f32x4 mfma16(short8 a, short8 b, f32x4 c) {
  return __builtin_amdgcn_mfma_f32_16x16x32_bf16(a, b, c, 0, 0, 0);
}
__device__ __forceinline__ short8 pk8(f32x4 x, f32x4 y) {
  short8 s;
  s[0] = (short)cvt1(x[0]); s[1] = (short)cvt1(x[1]);
  s[2] = (short)cvt1(x[2]); s[3] = (short)cvt1(x[3]);
  s[4] = (short)cvt1(y[0]); s[5] = (short)cvt1(y[1]);
  s[6] = (short)cvt1(y[2]); s[7] = (short)cvt1(y[3]);
  return s;
}

// ---------------- prep (grid 1280) -------------------------------------------
__global__ __launch_bounds__(256) void prep_all(
    const float* __restrict__ sub, const float* __restrict__ obj,
    const float* __restrict__ W1, const float* __restrict__ b1,
    const float* __restrict__ W2, const float* __restrict__ b2,
    const float* __restrict__ W3, const float* __restrict__ We,
    float* __restrict__ l1p, float* __restrict__ l2p,
    unsigned short* __restrict__ W3g, unsigned short* __restrict__ Weg) {
  const int tid = threadIdx.x;
  if (blockIdx.x >= 256) {
    int idx = (blockIdx.x - 256) * 256 + tid;
    if (idx < 196608) {
      int n = idx / 768, k = idx % 768;
      int f = ((k >> 5) * 256 + n) * 32 + ((k >> 3) & 3) * 8 + (k & 7);
      W3g[f] = f2bf(W3[idx]);
    }
    int j = idx - 196608;
    if (j >= 0 && j < 65536) {
      int n = j / 256, k = j % 256;
      int f = ((k >> 5) * 256 + n) * 32 + ((k >> 3) & 3) * 8 + (k & 7);
      Weg[f] = f2bf(We[j]);
    }
    return;
  }
  const int half = blockIdx.x >> 7;
  const float* x = half ? obj : sub;
  const float* W = half ? W2 : W1;
  const float* bias = half ? b2 : b1;
  float* outp = half ? l2p : l1p;

  __shared__ float xs[8][768];
  const int R0 = (blockIdx.x & 127) * 8;
  #pragma unroll
  for (int c = 0; c < 6; ++c) {
    int f4i = c * 256 + tid;
    int row = f4i / 192;
    int c4 = f4i % 192;
    *(float4*)&xs[row][c4 * 4] = *(const float4*)&x[(size_t)(R0 + row) * 768 + c4 * 4];
  }
  __syncthreads();
  const int col = tid;
  const float* Wr = W + (size_t)col * 768;
  float a[8] = {0.f, 0.f, 0.f, 0.f, 0.f, 0.f, 0.f, 0.f};
  for (int k4 = 0; k4 < 192; ++k4) {
    float4 wv = *(const float4*)&Wr[k4 * 4];
    #pragma unroll
    for (int r = 0; r < 8; ++r) {
      float4 xv = *(const float4*)&xs[r][k4 * 4];
      a[r] += wv.x * xv.x + wv.y * xv.y + wv.z * xv.z + wv.w * xv.w;
    }
  }
  float bb = bias[col];
  #pragma unroll
  for (int r = 0; r < 8; ++r)
    outp[(size_t)(R0 + r) * 256 + col] = a[r] + bb;
}

// ---------------- fused main -------------------------------------------------
__global__ __launch_bounds__(256, 4) void fused_main(
    const float* __restrict__ rel, const float* __restrict__ l1p,
    const float* __restrict__ l2p, const unsigned short* __restrict__ W3g,
    const unsigned short* __restrict__ Weg, const float* __restrict__ b3,
    const float* __restrict__ be, const float* __restrict__ lng,
    const float* __restrict__ lnb, float* __restrict__ out) {
  __shared__ union U {
    unsigned short stg[2][64][64];  // 16 KB bf16 staging (verified layout)
    unsigned short prod[64][256];   // 32 KB
  } u;
  __shared__ float ps[64][4], pq[64][4], mus[64], rss[64];  // 2.5 KB

  const int tid = threadIdx.x;
  const int wave = tid >> 6, lane = tid & 63;
  const int g = lane >> 4, c16 = lane & 15;

  // XCD-bijective swizzle (2048 % 8 == 0)
  const int bid = (blockIdx.x & 7) * 256 + (blockIdx.x >> 3);
  const int R0 = bid * 64;
  const int b = R0 >> 14;
  const int rem = R0 & 16383;
  const int i = rem >> 7;
  const int j0 = rem & 127;  // 0 or 64

  const float* relBase = rel + (size_t)((b * 128 + i) * 128 + j0) * 768;

  // staging geometry (verified): wave owns rows wave*16..+15.
  const int sr4 = lane >> 2, c4 = lane & 3;
  const int rr = wave * 16 + sr4;
  const float* aG = relBase + (size_t)rr * 768 + c4 * 16;
  unsigned short* stW0 = &u.stg[0][rr][((c4 * 2) ^ (rr & 7)) * 8];
  unsigned short* stW1 = &u.stg[0][rr][((c4 * 2 + 1) ^ (rr & 7)) * 8];

  // B: fragment-major W3g; n = wave*64 + fn*16 + c16
  const unsigned short* bp = W3g + (size_t)(wave * 64 + c16) * 32 + g * 8;

  f32x4 acc1[4][4] = {};
  f32x4 av[4];   // single-generation A prefetch (16 regs)
  short8 B_[8];  // current-tile B fragments (32 regs)

#define SCHED0 __builtin_amdgcn_sched_barrier(0)
#define RAW_BARRIER                                           \
  do {                                                        \
    SCHED0;                                                   \
    asm volatile("s_waitcnt lgkmcnt(0)" ::: "memory");        \
    SCHED0;                                                   \
    __builtin_amdgcn_s_barrier();                             \
    SCHED0;                                                   \
  } while (0)

#define LOADA(KS)                                                              \
  {                                                                            \
    const float* p_ = aG + (size_t)(KS) * 64;                                  \
    av[0] = *(const f32x4*)(p_);                                               \
    av[1] = *(const f32x4*)(p_ + 4);                                           \
    av[2] = *(const f32x4*)(p_ + 8);                                           \
    av[3] = *(const f32x4*)(p_ + 12);                                          \
  }
#define WRITEA(BUF)                                                            \
  {                                                                            \
    *(short8*)(stW0 + (BUF) * 4096) = pk8(av[0], av[1]);                       \
    *(short8*)(stW1 + (BUF) * 4096) = pk8(av[2], av[3]);                       \
  }

  // prologue: A(0) -> buf0
  LOADA(0);
  WRITEA(0);
  RAW_BARRIER;

  #pragma unroll
  for (int ks = 0; ks < 12; ++ks) {
    const int buf = ks & 1;
    // B(ks) first (L2-fast), A(ks+1) second (HBM-slow) — FIFO discipline
    #pragma unroll
    for (int sub = 0; sub < 2; ++sub)
      #pragma unroll
      for (int fn = 0; fn < 4; ++fn)
        B_[sub * 4 + fn] =
            *(const short8*)(bp + (size_t)(ks * 2 + sub) * 8192 + fn * 512);
    if (ks < 11) LOADA(ks + 1);
    SCHED0;
    // compute tile ks (compiler: counted vmcnt for B_, lgkmcnt for ds_read)
    __builtin_amdgcn_s_setprio(1);
    #pragma unroll
    for (int sub = 0; sub < 2; ++sub) {
      #pragma unroll
      for (int fm = 0; fm < 4; ++fm) {
        const int r = fm * 16 + c16;
        short8 ah = *(const short8*)&u.stg[buf][r][((sub * 4 + g) ^ (r & 7)) * 8];
        #pragma unroll
        for (int fn = 0; fn < 4; ++fn)
          acc1[fm][fn] = mfma16(ah, B_[sub * 4 + fn], acc1[fm][fn]);
      }
    }
    __builtin_amdgcn_s_setprio(0);
    SCHED0;
    // write A(ks+1) -> buf^1; raw barrier (lgkm only; A wait is counted vmcnt)
    if (ks < 11) {
      WRITEA(buf ^ 1);
      RAW_BARRIER;
    }
  }
  __syncthreads();  // queue empty; protects stg -> prod overlay

  // ---- epilogue 1: prod = (l3 + b3) * l1 * l2 -> bf16 swizzled LDS ----
  const int colb = wave * 64 + c16;
  const float* l1row = l1p + (size_t)(b * 128 + i) * 256;
  float l1v[4], b3v[4];
  #pragma unroll
  for (int fn = 0; fn < 4; ++fn) {
    l1v[fn] = l1row[colb + fn * 16];
    b3v[fn] = b3[colb + fn * 16];
  }
  #pragma unroll
  for (int fm = 0; fm < 4; ++fm) {
    #pragma unroll
    for (int r = 0; r < 4; ++r) {
      const int m = fm * 16 + g * 4 + r;
      const float* l2row = l2p + (size_t)(b * 128 + j0 + m) * 256;
      #pragma unroll
      for (int fn = 0; fn < 4; ++fn) {
        float v = (acc1[fm][fn][r] + b3v[fn]) * l1v[fn] * l2row[colb + fn * 16];
        u.prod[m][(colb + fn * 16) ^ ((m & 7) << 3)] = f2bf(v);
      }
    }
  }
  __syncthreads();

  // ---- GEMM2: f = prod @ Web^T (Weg fragment-major) ----
  f32x4 acc2[4][4] = {};
  #pragma unroll
  for (int kk = 0; kk < 8; ++kk) {
    short8 a2[4];
    #pragma unroll
    for (int fm = 0; fm < 4; ++fm) {
      const int m = fm * 16 + c16;
      a2[fm] = *(const short8*)&u.prod[m][(kk * 32 + g * 8) ^ ((m & 7) << 3)];
    }
    #pragma unroll
    for (int fn = 0; fn < 4; ++fn) {
      short8 bfr = *(const short8*)&Weg[(size_t)((kk * 256 + colb + fn * 16) * 4 + g) * 8];
      #pragma unroll
      for (int fm = 0; fm < 4; ++fm)
        acc2[fm][fn] = mfma16(a2[fm], bfr, acc2[fm][fn]);
    }
  }

  // ---- LN stats: per-row sum/sumsq; 16-lane shfl reduce + cross-wave LDS ----
  float bev[4];
  #pragma unroll
  for (int fn = 0; fn < 4; ++fn) bev[fn] = be[colb + fn * 16];
  #pragma unroll
  for (int fm = 0; fm < 4; ++fm) {
    #pragma unroll
    for (int r = 0; r < 4; ++r) {
      float s1 = 0.f, s2 = 0.f;
      #pragma unroll
      for (int fn = 0; fn < 4; ++fn) {
        float v = acc2[fm][fn][r] + bev[fn];
        s1 += v; s2 += v * v;
      }
      #pragma unroll
      for (int off = 1; off < 16; off <<= 1) {
        s1 += __shfl_xor(s1, off);
        s2 += __shfl_xor(s2, off);
      }
      if (c16 == 0) {
        const int m = fm * 16 + g * 4 + r;
        ps[m][wave] = s1; pq[m][wave] = s2;
      }
    }
  }
  __syncthreads();
  if (tid < 64) {
    float s = ps[tid][0] + ps[tid][1] + ps[tid][2] + ps[tid][3];
    float q = pq[tid][0] + pq[tid][1] + pq[tid][2] + pq[tid][3];
    float mu = s * 0.00390625f;
    float var = q * 0.00390625f - mu * mu;
    mus[tid] = mu;
    rss[tid] = rsqrtf(var + 1e-6f);
  }
  __syncthreads();

  // ---- store: (f - mu)*rs*g + b ----
  float gv[4], bhv[4];
  #pragma unroll
  for (int fn = 0; fn < 4; ++fn) {
    gv[fn] = lng[colb + fn * 16];
    bhv[fn] = lnb[colb + fn * 16];
  }
  #pragma unroll
  for (int fm = 0; fm < 4; ++fm) {
    #pragma unroll
    for (int r = 0; r < 4; ++r) {
      const int m = fm * 16 + g * 4 + r;
      const float mu = mus[m], rs = rss[m];
      float* orow = out + (size_t)(R0 + m) * 256;
      #pragma unroll
      for (int fn = 0; fn < 4; ++fn) {
        float v = acc2[fm][fn][r] + bev[fn];
        orow[colb + fn * 16] = (v - mu) * rs * gv[fn] + bhv[fn];
      }
    }
  }
#undef SCHED0
#undef RAW_BARRIER
#undef LOADA
#undef WRITEA
}

extern "C" void kernel_launch(void* const* d_in, const int* in_sizes, int n_in,
                              void* d_out, int out_size, void* d_ws, size_t ws_size,
                              hipStream_t stream) {
  const float* sub = (const float*)d_in[0];
  const float* obj = (const float*)d_in[1];
  const float* rel = (const float*)d_in[2];
  const float* W1 = (const float*)d_in[3];
  const float* b1 = (const float*)d_in[4];
  const float* W2 = (const float*)d_in[5];
  const float* b2 = (const float*)d_in[6];
  const float* W3 = (const float*)d_in[7];
  const float* b3 = (const float*)d_in[8];
  const float* We = (const float*)d_in[9];
  const float* be = (const float*)d_in[10];
  const float* lng = (const float*)d_in[11];
  const float* lnb = (const float*)d_in[12];
  float* out = (float*)d_out;

  float* ws = (float*)d_ws;
  float* l1p = ws;
  float* l2p = ws + 262144;
  unsigned short* W3g = (unsigned short*)(ws + 524288);
  unsigned short* Weg = W3g + 196608;

  prep_all<<<1280, 256, 0, stream>>>(sub, obj, W1, b1, W2, b2, W3, We, l1p, l2p, W3g, Weg);
  fused_main<<<2048, 256, 0, stream>>>(rel, l1p, l2p, W3g, Weg, b3, be, lng, lnb, out);
}